// Round 1
// baseline (424.755 us; speedup 1.0000x reference)
//
#include <hip/hip_runtime.h>
#include <hip/hip_bf16.h>

#define KD   544      // 512 state + x0,x1,1 + pad to 17*32
#define ASTR 552      // LDS row stride (bf16): 1104B, 16B aligned, bank-staggered
#define RPB  64       // rows per block
#define THR  512      // 8 waves

typedef __bf16 bf8 __attribute__((ext_vector_type(8)));
typedef float f32x4 __attribute__((ext_vector_type(4)));

__device__ __forceinline__ float sigm(float x)  { return 1.0f / (1.0f + __expf(-x)); }
__device__ __forceinline__ float tanh_(float x) { return 2.0f / (1.0f + __expf(-2.0f * x)) - 1.0f; }

// Pack [Wh; Wx; bias] -> whT[2048][544] bf16, row j = gate*512 + outcol, k-major contiguous.
__global__ void pack_whT(const float* __restrict__ Wi_h, const float* __restrict__ Wf_h,
                         const float* __restrict__ Wc_h, const float* __restrict__ Wo_h,
                         const float* __restrict__ Wi_x, const float* __restrict__ Wf_x,
                         const float* __restrict__ Wc_x, const float* __restrict__ Wo_x,
                         const float* __restrict__ bi_x, const float* __restrict__ bf_x,
                         const float* __restrict__ bc_x, const float* __restrict__ bo_x,
                         const float* __restrict__ bi_h, const float* __restrict__ bf_h,
                         const float* __restrict__ bc_h, const float* __restrict__ bo_h,
                         __bf16* __restrict__ whT)
{
  int idx = blockIdx.x * 256 + threadIdx.x;
  if (idx >= 2048 * KD) return;
  int j = idx / KD, k = idx % KD;
  int g = j >> 9, c = j & 511;
  const float* Wh = (g == 0) ? Wi_h : (g == 1) ? Wf_h : (g == 2) ? Wc_h : Wo_h;
  const float* Wx = (g == 0) ? Wi_x : (g == 1) ? Wf_x : (g == 2) ? Wc_x : Wo_x;
  const float* bx = (g == 0) ? bi_x : (g == 1) ? bf_x : (g == 2) ? bc_x : bo_x;
  const float* bh = (g == 0) ? bi_h : (g == 1) ? bf_h : (g == 2) ? bc_h : bo_h;
  float v = 0.0f;
  if (k < 512)       v = Wh[k * 512 + c];
  else if (k == 512) v = Wx[c];
  else if (k == 513) v = Wx[512 + c];
  else if (k == 514) v = bx[c] + bh[c];
  whT[idx] = (__bf16)v;
}

// Pack [out_W1 | halt_W1] -> w1cat[256][544] bf16 (bias folded at k=514, zeros at x rows).
__global__ void pack_w1cat(const float* __restrict__ outW1, const float* __restrict__ outb1,
                           const float* __restrict__ haltW1, const float* __restrict__ haltb1,
                           __bf16* __restrict__ w1cat)
{
  int idx = blockIdx.x * 256 + threadIdx.x;
  if (idx >= 256 * KD) return;
  int j = idx / KD, k = idx % KD;
  float v = 0.0f;
  if (j < 128) {
    if (k < 512)       v = outW1[k * 128 + j];
    else if (k == 514) v = outb1[j];
  } else {
    int jj = j - 128;
    if (k < 512)       v = haltW1[k * 128 + jj];
    else if (k == 514) v = haltb1[jj];
  }
  w1cat[idx] = (__bf16)v;
}

// w23 = out_W2 @ out_W3 (128), b23 = out_b2 @ out_W3 + out_b3.
__global__ void pack_w23(const float* __restrict__ outW2, const float* __restrict__ outb2,
                         const float* __restrict__ outW3, const float* __restrict__ outb3,
                         float* __restrict__ w23, float* __restrict__ b23)
{
  int c1 = threadIdx.x;
  float s = 0.0f;
  for (int c2 = 0; c2 < 128; ++c2) s += outW2[c1 * 128 + c2] * outW3[c2];
  w23[c1] = s;
  if (c1 == 0) {
    float b = 0.0f;
    for (int c2 = 0; c2 < 128; ++c2) b += outb2[c2] * outW3[c2];
    b23[0] = b + outb3[0];
  }
}

__global__ __launch_bounds__(THR, 2) void act_main(
    const float* __restrict__ x,
    const __bf16* __restrict__ whT,
    const __bf16* __restrict__ w1cat,
    const float* __restrict__ w23,
    const float* __restrict__ b23p,
    const float* __restrict__ haltW2,
    const float* __restrict__ haltb2,
    float* __restrict__ out)
{
  __shared__ __align__(16) __bf16 Abuf[2][RPB][ASTR];
  __shared__ float wv[256];          // [0:128) w23, [128:256) halt_W2
  __shared__ float partials[8][RPB];
  __shared__ int anyact_s;

  const int tid  = threadIdx.x;
  const int wave = tid >> 6;
  const int lane = tid & 63;
  const int lg   = lane >> 4;   // k-group / D-row-group
  const int lc   = lane & 15;   // A-row / D-col within tile
  const int row0 = blockIdx.x * RPB;

  if (tid < 256) wv[tid] = (tid < 128) ? w23[tid] : haltW2[tid - 128];
  for (int idx = tid; idx < 2 * RPB * ASTR; idx += THR) {
    int b = idx / (RPB * ASTR);
    int rem = idx - b * (RPB * ASTR);
    int r = rem / ASTR;
    int k = rem - r * ASTR;
    float v = 0.0f;
    if (k == 512)      v = x[(row0 + r) * 2 + 0];
    else if (k == 513) v = x[(row0 + r) * 2 + 1];
    else if (k == 514) v = 1.0f;
    Abuf[b][r][k] = (__bf16)v;
  }
  if (tid == 0) anyact_s = 1;
  __syncthreads();

  float cell[4][4][4];  // [ncol-tile][m-tile][reg] — statically indexed, lives in VGPRs
#pragma unroll
  for (int n = 0; n < 4; ++n)
#pragma unroll
    for (int m = 0; m < 4; ++m)
#pragma unroll
      for (int q = 0; q < 4; ++q) cell[n][m][q] = 0.0f;

  bool  active = (tid < 64);
  float p_sum = 0.0f, accum = 0.0f;
  const float b23 = b23p[0];
  const float bh2 = haltb2[0];
  const f32x4 zero4 = {0.0f, 0.0f, 0.0f, 0.0f};

  int cur = 0;
  for (int t = 0; t < 32; ++t) {
    const int kstart = (t == 0) ? 16 : 0;   // state==0 at t=0: only the x/bias k-step
    // ---------------- gate GEMM (64 x 2048) + LSTM update ----------------
#pragma unroll
    for (int n = 0; n < 4; ++n) {
      const int colb = wave * 64 + n * 16 + lc;   // hidden col c0 this lane's B/D covers
      const __bf16* bp0 = whT + (size_t)(colb)        * KD + lg * 8;
      const __bf16* bp1 = whT + (size_t)(512  + colb) * KD + lg * 8;
      const __bf16* bp2 = whT + (size_t)(1024 + colb) * KD + lg * 8;
      const __bf16* bp3 = whT + (size_t)(1536 + colb) * KD + lg * 8;
      f32x4 acc[4][4];
#pragma unroll
      for (int g = 0; g < 4; ++g)
#pragma unroll
        for (int m = 0; m < 4; ++m) acc[g][m] = zero4;

      bf8 b0 = *(const bf8*)(bp0 + kstart * 32);
      bf8 b1 = *(const bf8*)(bp1 + kstart * 32);
      bf8 b2 = *(const bf8*)(bp2 + kstart * 32);
      bf8 b3 = *(const bf8*)(bp3 + kstart * 32);
#pragma unroll 1
      for (int kk = kstart; kk < 16; ++kk) {
        bf8 av[4];
#pragma unroll
        for (int m = 0; m < 4; ++m)
          av[m] = *(const bf8*)&Abuf[cur][m * 16 + lc][kk * 32 + lg * 8];
        bf8 nb0 = *(const bf8*)(bp0 + (kk + 1) * 32);
        bf8 nb1 = *(const bf8*)(bp1 + (kk + 1) * 32);
        bf8 nb2 = *(const bf8*)(bp2 + (kk + 1) * 32);
        bf8 nb3 = *(const bf8*)(bp3 + (kk + 1) * 32);
#pragma unroll
        for (int m = 0; m < 4; ++m) {
          acc[0][m] = __builtin_amdgcn_mfma_f32_16x16x32_bf16(av[m], b0, acc[0][m], 0, 0, 0);
          acc[1][m] = __builtin_amdgcn_mfma_f32_16x16x32_bf16(av[m], b1, acc[1][m], 0, 0, 0);
          acc[2][m] = __builtin_amdgcn_mfma_f32_16x16x32_bf16(av[m], b2, acc[2][m], 0, 0, 0);
          acc[3][m] = __builtin_amdgcn_mfma_f32_16x16x32_bf16(av[m], b3, acc[3][m], 0, 0, 0);
        }
        b0 = nb0; b1 = nb1; b2 = nb2; b3 = nb3;
      }
      { // tail k-step (kk = 16: x0,x1,bias rows)
        bf8 av[4];
#pragma unroll
        for (int m = 0; m < 4; ++m)
          av[m] = *(const bf8*)&Abuf[cur][m * 16 + lc][16 * 32 + lg * 8];
#pragma unroll
        for (int m = 0; m < 4; ++m) {
          acc[0][m] = __builtin_amdgcn_mfma_f32_16x16x32_bf16(av[m], b0, acc[0][m], 0, 0, 0);
          acc[1][m] = __builtin_amdgcn_mfma_f32_16x16x32_bf16(av[m], b1, acc[1][m], 0, 0, 0);
          acc[2][m] = __builtin_amdgcn_mfma_f32_16x16x32_bf16(av[m], b2, acc[2][m], 0, 0, 0);
          acc[3][m] = __builtin_amdgcn_mfma_f32_16x16x32_bf16(av[m], b3, acc[3][m], 0, 0, 0);
        }
      }
      // LSTM update epilogue. D layout: col = lane&15, row = (lane>>4)*4 + reg (+m*16)
#pragma unroll
      for (int m = 0; m < 4; ++m) {
#pragma unroll
        for (int q = 0; q < 4; ++q) {
          float iv = sigm(acc[0][m][q]);
          float fv = sigm(acc[1][m][q]);
          float cv = tanh_(acc[2][m][q]);
          float ov = sigm(acc[3][m][q]);
          float cn = fv * cell[n][m][q] + iv * cv;
          cell[n][m][q] = cn;
          float h = ov * tanh_(cn);
          Abuf[cur ^ 1][m * 16 + lg * 4 + q][colb] = (__bf16)h;
        }
      }
    }
    __syncthreads();
    // ---------------- head GEMM (64 x 256 = out|halt) + folded dots ----------------
    {
      const int jb0 = wave * 32 + lc;
      const __bf16* hp0 = w1cat + (size_t)jb0        * KD + lg * 8;
      const __bf16* hp1 = w1cat + (size_t)(jb0 + 16) * KD + lg * 8;
      f32x4 hacc[2][4];
#pragma unroll
      for (int n2 = 0; n2 < 2; ++n2)
#pragma unroll
        for (int m = 0; m < 4; ++m) hacc[n2][m] = zero4;
      bf8 hb0 = *(const bf8*)(hp0);
      bf8 hb1 = *(const bf8*)(hp1);
#pragma unroll 1
      for (int kk = 0; kk < 16; ++kk) {
        bf8 av[4];
#pragma unroll
        for (int m = 0; m < 4; ++m)
          av[m] = *(const bf8*)&Abuf[cur ^ 1][m * 16 + lc][kk * 32 + lg * 8];
        bf8 nb0 = *(const bf8*)(hp0 + (kk + 1) * 32);
        bf8 nb1 = *(const bf8*)(hp1 + (kk + 1) * 32);
#pragma unroll
        for (int m = 0; m < 4; ++m) {
          hacc[0][m] = __builtin_amdgcn_mfma_f32_16x16x32_bf16(av[m], hb0, hacc[0][m], 0, 0, 0);
          hacc[1][m] = __builtin_amdgcn_mfma_f32_16x16x32_bf16(av[m], hb1, hacc[1][m], 0, 0, 0);
        }
        hb0 = nb0; hb1 = nb1;
      }
      {
        bf8 av[4];
#pragma unroll
        for (int m = 0; m < 4; ++m)
          av[m] = *(const bf8*)&Abuf[cur ^ 1][m * 16 + lc][16 * 32 + lg * 8];
#pragma unroll
        for (int m = 0; m < 4; ++m) {
          hacc[0][m] = __builtin_amdgcn_mfma_f32_16x16x32_bf16(av[m], hb0, hacc[0][m], 0, 0, 0);
          hacc[1][m] = __builtin_amdgcn_mfma_f32_16x16x32_bf16(av[m], hb1, hacc[1][m], 0, 0, 0);
        }
      }
      const float wv0 = wv[wave * 32 + lc];
      const float wv1 = wv[wave * 32 + 16 + lc];
#pragma unroll
      for (int m = 0; m < 4; ++m) {
#pragma unroll
        for (int q = 0; q < 4; ++q) {
          float s = fmaxf(hacc[0][m][q], 0.0f) * wv0 + fmaxf(hacc[1][m][q], 0.0f) * wv1;
          s += __shfl_xor(s, 1, 64);
          s += __shfl_xor(s, 2, 64);
          s += __shfl_xor(s, 4, 64);
          s += __shfl_xor(s, 8, 64);
          if (lc == 0) partials[wave][m * 16 + lg * 4 + q] = s;
        }
      }
    }
    __syncthreads();
    // ---------------- ACT bookkeeping (wave 0, one lane per row) ----------------
    if (tid < 64) {
      float od = partials[0][tid] + partials[1][tid] + partials[2][tid] + partials[3][tid] + b23;
      float hd = partials[4][tid] + partials[5][tid] + partials[6][tid] + partials[7][tid] + bh2;
      float outv  = sigm(od);
      float haltv = sigm(hd);
      if (active) {
        float pn  = p_sum + haltv;
        bool  fin = (pn >= 0.999f) || (t == 31);
        accum += outv * (fin ? (haltv + (1.0f - pn)) : haltv);
        p_sum  = fin ? 1.0f : pn;
        active = !fin;
      }
      unsigned long long mk = __ballot(active);
      if (tid == 0) anyact_s = (mk != 0ull) ? 1 : 0;
    }
    __syncthreads();
    if (!anyact_s) break;
    cur ^= 1;
  }
  if (tid < 64) out[row0 + tid] = accum;
}

extern "C" void kernel_launch(void* const* d_in, const int* in_sizes, int n_in,
                              void* d_out, int out_size, void* d_ws, size_t ws_size,
                              hipStream_t stream) {
  const float* x     = (const float*)d_in[0];
  const float* Wi_x  = (const float*)d_in[1];
  const float* bi_x  = (const float*)d_in[2];
  const float* Wi_h  = (const float*)d_in[3];
  const float* bi_h  = (const float*)d_in[4];
  const float* Wf_x  = (const float*)d_in[5];
  const float* bf_x  = (const float*)d_in[6];
  const float* Wf_h  = (const float*)d_in[7];
  const float* bf_h  = (const float*)d_in[8];
  const float* Wc_x  = (const float*)d_in[9];
  const float* bc_x  = (const float*)d_in[10];
  const float* Wc_h  = (const float*)d_in[11];
  const float* bc_h  = (const float*)d_in[12];
  const float* Wo_x  = (const float*)d_in[13];
  const float* bo_x  = (const float*)d_in[14];
  const float* Wo_h  = (const float*)d_in[15];
  const float* bo_h  = (const float*)d_in[16];
  const float* hW1   = (const float*)d_in[17];
  const float* hb1   = (const float*)d_in[18];
  const float* hW2   = (const float*)d_in[19];
  const float* hb2   = (const float*)d_in[20];
  const float* oW1   = (const float*)d_in[21];
  const float* ob1   = (const float*)d_in[22];
  const float* oW2   = (const float*)d_in[23];
  const float* ob2   = (const float*)d_in[24];
  const float* oW3   = (const float*)d_in[25];
  const float* ob3   = (const float*)d_in[26];

  __bf16* whT   = (__bf16*)d_ws;
  __bf16* w1cat = whT + (size_t)2048 * KD;
  float*  w23   = (float*)(w1cat + (size_t)256 * KD);
  float*  b23   = w23 + 128;

  pack_whT<<<dim3((2048 * KD + 255) / 256), dim3(256), 0, stream>>>(
      Wi_h, Wf_h, Wc_h, Wo_h, Wi_x, Wf_x, Wc_x, Wo_x,
      bi_x, bf_x, bc_x, bo_x, bi_h, bf_h, bc_h, bo_h, whT);
  pack_w1cat<<<dim3((256 * KD + 255) / 256), dim3(256), 0, stream>>>(oW1, ob1, hW1, hb1, w1cat);
  pack_w23<<<dim3(1), dim3(128), 0, stream>>>(oW2, ob2, oW3, ob3, w23, b23);
  act_main<<<dim3(32768 / RPB), dim3(THR), 0, stream>>>(
      x, whT, w1cat, w23, b23, hW2, hb2, (float*)d_out);
}

// Round 2
// 407.307 us; speedup vs baseline: 1.0428x; 1.0428x over previous
//
#include <hip/hip_runtime.h>
#include <hip/hip_bf16.h>

#define KD   544      // 512 state + x0,x1,1 + pad to 17*32
#define ASTR 552      // LDS row stride (bf16): 1104B = 69*16B (odd *16B -> conflict-benign)
#define RPB  64       // rows per block
#define THR  512      // 8 waves
#define T1   3        // pass-1 step count
#define NROW 32768

typedef __bf16 bf8 __attribute__((ext_vector_type(8)));
typedef float f32x4 __attribute__((ext_vector_type(4)));

__device__ __forceinline__ float sigm(float x)  { return 1.0f / (1.0f + __expf(-x)); }
__device__ __forceinline__ float tanh_(float x) { return 2.0f / (1.0f + __expf(-2.0f * x)) - 1.0f; }

// One launch packs everything:
//  blocks [0,4352)    : whT[2048][544]  (gate weights, k-major, x/bias folded)
//  blocks [4352,4896) : w1cat[256][544] (out_W1 | halt_W1, bias folded)
//  block  4896        : w23/b23 fold + zero survivor counter
__global__ void pack_all(const float* __restrict__ Wi_h, const float* __restrict__ Wf_h,
                         const float* __restrict__ Wc_h, const float* __restrict__ Wo_h,
                         const float* __restrict__ Wi_x, const float* __restrict__ Wf_x,
                         const float* __restrict__ Wc_x, const float* __restrict__ Wo_x,
                         const float* __restrict__ bi_x, const float* __restrict__ bf_x,
                         const float* __restrict__ bc_x, const float* __restrict__ bo_x,
                         const float* __restrict__ bi_h, const float* __restrict__ bf_h,
                         const float* __restrict__ bc_h, const float* __restrict__ bo_h,
                         const float* __restrict__ outW1, const float* __restrict__ outb1,
                         const float* __restrict__ haltW1, const float* __restrict__ haltb1,
                         const float* __restrict__ outW2, const float* __restrict__ outb2,
                         const float* __restrict__ outW3, const float* __restrict__ outb3,
                         __bf16* __restrict__ whT, __bf16* __restrict__ w1cat,
                         float* __restrict__ w23, float* __restrict__ b23,
                         int* __restrict__ cntp)
{
  int b = blockIdx.x;
  if (b < 4352) {
    int idx = b * 256 + threadIdx.x;           // < 2048*544 exactly
    int j = idx / KD, k = idx % KD;
    int g = j >> 9, c = j & 511;
    const float* Wh = (g == 0) ? Wi_h : (g == 1) ? Wf_h : (g == 2) ? Wc_h : Wo_h;
    const float* Wx = (g == 0) ? Wi_x : (g == 1) ? Wf_x : (g == 2) ? Wc_x : Wo_x;
    const float* bx = (g == 0) ? bi_x : (g == 1) ? bf_x : (g == 2) ? bc_x : bo_x;
    const float* bh = (g == 0) ? bi_h : (g == 1) ? bf_h : (g == 2) ? bc_h : bo_h;
    float v = 0.0f;
    if (k < 512)       v = Wh[k * 512 + c];
    else if (k == 512) v = Wx[c];
    else if (k == 513) v = Wx[512 + c];
    else if (k == 514) v = bx[c] + bh[c];
    whT[idx] = (__bf16)v;
  } else if (b < 4896) {
    int idx = (b - 4352) * 256 + threadIdx.x;  // < 256*544 exactly
    int j = idx / KD, k = idx % KD;
    float v = 0.0f;
    if (j < 128) {
      if (k < 512)       v = outW1[k * 128 + j];
      else if (k == 514) v = outb1[j];
    } else {
      int jj = j - 128;
      if (k < 512)       v = haltW1[k * 128 + jj];
      else if (k == 514) v = haltb1[jj];
    }
    w1cat[idx] = (__bf16)v;
  } else {
    int c1 = threadIdx.x;
    if (c1 < 128) {
      float s = 0.0f;
      for (int c2 = 0; c2 < 128; ++c2) s += outW2[c1 * 128 + c2] * outW3[c2];
      w23[c1] = s;
    }
    if (c1 == 0) {
      float bb = 0.0f;
      for (int c2 = 0; c2 < 128; ++c2) bb += outb2[c2] * outW3[c2];
      b23[0] = bb + outb3[0];
      cntp[0] = 0;
    }
  }
}

template<bool P1>
__global__ __launch_bounds__(THR, 2) void act_pass(
    const float* __restrict__ x,
    const __bf16* __restrict__ whT,
    const __bf16* __restrict__ w1cat,
    const float* __restrict__ w23,
    const float* __restrict__ b23p,
    const float* __restrict__ haltW2,
    const float* __restrict__ haltb2,
    __bf16* __restrict__ sstate,
    __bf16* __restrict__ scell,
    float* __restrict__ spsum,
    float* __restrict__ saccum,
    int* __restrict__ sidx,
    int* __restrict__ cntp,
    float* __restrict__ out)
{
  int cnt_v = 0, sbase = 0;
  if constexpr (!P1) {
    cnt_v = cntp[0];
    sbase = blockIdx.x * RPB;
    if (sbase >= cnt_v) return;   // uniform early exit for empty pass-2 blocks
  }

  __shared__ __align__(16) __bf16 Abuf[2][RPB][ASTR];
  __shared__ float wv[256];          // [0:128) w23, [128:256) halt_W2
  __shared__ float partials[8][RPB];
  __shared__ int anyact_s;
  __shared__ int rowslot[RPB];

  const int tid  = threadIdx.x;
  const int wave = tid >> 6;
  const int lane = tid & 63;
  const int lg   = lane >> 4;
  const int lc   = lane & 15;
  const int row0 = blockIdx.x * RPB;

  if (tid < 256) wv[tid] = (tid < 128) ? w23[tid] : haltW2[tid - 128];

  if constexpr (P1) {
    // zero both buffers (16B chunks), fold x + bias-one into cols 512..514
    for (int w = tid; w < 2 * RPB * 69; w += THR) {
      int bb  = w / (RPB * 69);
      int rem = w - bb * (RPB * 69);
      int r   = rem / 69;
      int j   = rem - r * 69;
      bf8 v;
#pragma unroll
      for (int e = 0; e < 8; ++e) v[e] = (__bf16)0.0f;
      if (j == 64) {
        v[0] = (__bf16)x[(row0 + r) * 2 + 0];
        v[1] = (__bf16)x[(row0 + r) * 2 + 1];
        v[2] = (__bf16)1.0f;
      }
      *(bf8*)&Abuf[bb][r][j * 8] = v;
    }
  } else {
    // gather survivor state into Abuf[0] (full 544 cols), cell into Abuf[1][:,0:512),
    // and state tail cols into Abuf[1][:,512:544) so buffer-1 is a valid A source later.
    for (int w = tid; w < RPB * 68; w += THR) {
      int r = w / 68, j = w - r * 68;
      int slot = sbase + r;
      bf8 v;
#pragma unroll
      for (int e = 0; e < 8; ++e) v[e] = (__bf16)0.0f;
      if (slot < cnt_v) v = *(const bf8*)(sstate + (size_t)slot * KD + j * 8);
      *(bf8*)&Abuf[0][r][j * 8] = v;
      if (j >= 64) *(bf8*)&Abuf[1][r][j * 8] = v;   // tail cols 512..543
    }
    for (int w = tid; w < RPB * 64; w += THR) {
      int r = w / 64, j = w - r * 64;
      int slot = sbase + r;
      bf8 v;
#pragma unroll
      for (int e = 0; e < 8; ++e) v[e] = (__bf16)0.0f;
      if (slot < cnt_v) v = *(const bf8*)(scell + (size_t)slot * 512 + j * 8);
      *(bf8*)&Abuf[1][r][j * 8] = v;
    }
  }
  if (tid == 0) anyact_s = 1;
  __syncthreads();

  float cell[4][4][4];
  if constexpr (P1) {
#pragma unroll
    for (int n = 0; n < 4; ++n)
#pragma unroll
      for (int m = 0; m < 4; ++m)
#pragma unroll
        for (int q = 0; q < 4; ++q) cell[n][m][q] = 0.0f;
  } else {
#pragma unroll
    for (int n = 0; n < 4; ++n)
#pragma unroll
      for (int m = 0; m < 4; ++m)
#pragma unroll
        for (int q = 0; q < 4; ++q)
          cell[n][m][q] = (float)Abuf[1][m * 16 + lg * 4 + q][wave * 64 + n * 16 + lc];
  }

  bool  valid, active;
  float p_sum, accum;
  int   oidx;
  if constexpr (P1) {
    valid = (tid < 64); active = valid;
    p_sum = 0.0f; accum = 0.0f; oidx = row0 + tid;
  } else {
    int slot = sbase + tid;
    valid = (tid < 64) && (slot < cnt_v);
    active = valid;
    p_sum = valid ? spsum[slot]  : 1.0f;
    accum = valid ? saccum[slot] : 0.0f;
    oidx  = valid ? sidx[slot]   : 0;
    __syncthreads();   // cell regs consumed from Abuf[1] before epilogue overwrites it
  }

  const float b23 = b23p[0];
  const float bh2 = haltb2[0];
  const f32x4 zero4 = {0.0f, 0.0f, 0.0f, 0.0f};

  int cur = 0;
  const int T0 = P1 ? 0 : T1;
  const int TE = P1 ? T1 : 32;
  for (int t = T0; t < TE; ++t) {
    const int kstart = (P1 && t == 0) ? 16 : 0;   // state==0 at global t=0
    // ---------------- gate GEMM (64 x 2048) + LSTM update ----------------
#pragma unroll
    for (int n = 0; n < 4; ++n) {
      const int colb = wave * 64 + n * 16 + lc;
      const __bf16* bp0 = whT + (size_t)(colb)        * KD + lg * 8;
      const __bf16* bp1 = whT + (size_t)(512  + colb) * KD + lg * 8;
      const __bf16* bp2 = whT + (size_t)(1024 + colb) * KD + lg * 8;
      const __bf16* bp3 = whT + (size_t)(1536 + colb) * KD + lg * 8;
      f32x4 acc[4][4];
#pragma unroll
      for (int g = 0; g < 4; ++g)
#pragma unroll
        for (int m = 0; m < 4; ++m) acc[g][m] = zero4;

      bf8 b0 = *(const bf8*)(bp0 + kstart * 32);
      bf8 b1 = *(const bf8*)(bp1 + kstart * 32);
      bf8 b2 = *(const bf8*)(bp2 + kstart * 32);
      bf8 b3 = *(const bf8*)(bp3 + kstart * 32);
#pragma unroll 1
      for (int kk = kstart; kk < 16; ++kk) {
        bf8 av[4];
#pragma unroll
        for (int m = 0; m < 4; ++m)
          av[m] = *(const bf8*)&Abuf[cur][m * 16 + lc][kk * 32 + lg * 8];
        bf8 nb0 = *(const bf8*)(bp0 + (kk + 1) * 32);
        bf8 nb1 = *(const bf8*)(bp1 + (kk + 1) * 32);
        bf8 nb2 = *(const bf8*)(bp2 + (kk + 1) * 32);
        bf8 nb3 = *(const bf8*)(bp3 + (kk + 1) * 32);
#pragma unroll
        for (int m = 0; m < 4; ++m) {
          acc[0][m] = __builtin_amdgcn_mfma_f32_16x16x32_bf16(av[m], b0, acc[0][m], 0, 0, 0);
          acc[1][m] = __builtin_amdgcn_mfma_f32_16x16x32_bf16(av[m], b1, acc[1][m], 0, 0, 0);
          acc[2][m] = __builtin_amdgcn_mfma_f32_16x16x32_bf16(av[m], b2, acc[2][m], 0, 0, 0);
          acc[3][m] = __builtin_amdgcn_mfma_f32_16x16x32_bf16(av[m], b3, acc[3][m], 0, 0, 0);
        }
        b0 = nb0; b1 = nb1; b2 = nb2; b3 = nb3;
      }
      { // tail k-step (x0,x1,bias rows)
        bf8 av[4];
#pragma unroll
        for (int m = 0; m < 4; ++m)
          av[m] = *(const bf8*)&Abuf[cur][m * 16 + lc][16 * 32 + lg * 8];
#pragma unroll
        for (int m = 0; m < 4; ++m) {
          acc[0][m] = __builtin_amdgcn_mfma_f32_16x16x32_bf16(av[m], b0, acc[0][m], 0, 0, 0);
          acc[1][m] = __builtin_amdgcn_mfma_f32_16x16x32_bf16(av[m], b1, acc[1][m], 0, 0, 0);
          acc[2][m] = __builtin_amdgcn_mfma_f32_16x16x32_bf16(av[m], b2, acc[2][m], 0, 0, 0);
          acc[3][m] = __builtin_amdgcn_mfma_f32_16x16x32_bf16(av[m], b3, acc[3][m], 0, 0, 0);
        }
      }
#pragma unroll
      for (int m = 0; m < 4; ++m) {
#pragma unroll
        for (int q = 0; q < 4; ++q) {
          float iv = sigm(acc[0][m][q]);
          float fv = sigm(acc[1][m][q]);
          float cv = tanh_(acc[2][m][q]);
          float ov = sigm(acc[3][m][q]);
          float cn = fv * cell[n][m][q] + iv * cv;
          cell[n][m][q] = cn;
          float h = ov * tanh_(cn);
          Abuf[cur ^ 1][m * 16 + lg * 4 + q][colb] = (__bf16)h;
        }
      }
    }
    __syncthreads();
    // ---------------- head GEMM (64 x 256 = out|halt) + folded dots ----------------
    {
      const int jb0 = wave * 32 + lc;
      const __bf16* hp0 = w1cat + (size_t)jb0        * KD + lg * 8;
      const __bf16* hp1 = w1cat + (size_t)(jb0 + 16) * KD + lg * 8;
      f32x4 hacc[2][4];
#pragma unroll
      for (int n2 = 0; n2 < 2; ++n2)
#pragma unroll
        for (int m = 0; m < 4; ++m) hacc[n2][m] = zero4;
      bf8 hb0 = *(const bf8*)(hp0);
      bf8 hb1 = *(const bf8*)(hp1);
#pragma unroll 1
      for (int kk = 0; kk < 16; ++kk) {
        bf8 av[4];
#pragma unroll
        for (int m = 0; m < 4; ++m)
          av[m] = *(const bf8*)&Abuf[cur ^ 1][m * 16 + lc][kk * 32 + lg * 8];
        bf8 nb0 = *(const bf8*)(hp0 + (kk + 1) * 32);
        bf8 nb1 = *(const bf8*)(hp1 + (kk + 1) * 32);
#pragma unroll
        for (int m = 0; m < 4; ++m) {
          hacc[0][m] = __builtin_amdgcn_mfma_f32_16x16x32_bf16(av[m], hb0, hacc[0][m], 0, 0, 0);
          hacc[1][m] = __builtin_amdgcn_mfma_f32_16x16x32_bf16(av[m], hb1, hacc[1][m], 0, 0, 0);
        }
        hb0 = nb0; hb1 = nb1;
      }
      {
        bf8 av[4];
#pragma unroll
        for (int m = 0; m < 4; ++m)
          av[m] = *(const bf8*)&Abuf[cur ^ 1][m * 16 + lc][16 * 32 + lg * 8];
#pragma unroll
        for (int m = 0; m < 4; ++m) {
          hacc[0][m] = __builtin_amdgcn_mfma_f32_16x16x32_bf16(av[m], hb0, hacc[0][m], 0, 0, 0);
          hacc[1][m] = __builtin_amdgcn_mfma_f32_16x16x32_bf16(av[m], hb1, hacc[1][m], 0, 0, 0);
        }
      }
      const float wv0 = wv[wave * 32 + lc];
      const float wv1 = wv[wave * 32 + 16 + lc];
#pragma unroll
      for (int m = 0; m < 4; ++m) {
#pragma unroll
        for (int q = 0; q < 4; ++q) {
          float s = fmaxf(hacc[0][m][q], 0.0f) * wv0 + fmaxf(hacc[1][m][q], 0.0f) * wv1;
          s += __shfl_xor(s, 1, 64);
          s += __shfl_xor(s, 2, 64);
          s += __shfl_xor(s, 4, 64);
          s += __shfl_xor(s, 8, 64);
          if (lc == 0) partials[wave][m * 16 + lg * 4 + q] = s;
        }
      }
    }
    __syncthreads();
    // ---------------- ACT bookkeeping ----------------
    if (tid < 64) {
      float od = partials[0][tid] + partials[1][tid] + partials[2][tid] + partials[3][tid] + b23;
      float hd = partials[4][tid] + partials[5][tid] + partials[6][tid] + partials[7][tid] + bh2;
      float outv  = sigm(od);
      float haltv = sigm(hd);
      if (active) {
        float pn  = p_sum + haltv;
        bool  fin = (pn >= 0.999f) || (t == 31);
        accum += outv * (fin ? (haltv + (1.0f - pn)) : haltv);
        p_sum  = fin ? 1.0f : pn;
        active = !fin;
      }
      unsigned long long mk = __ballot(active);
      if (tid == 0) anyact_s = (mk != 0ull) ? 1 : 0;
    }
    __syncthreads();
    if (!anyact_s) break;
    cur ^= 1;
  }

  if constexpr (P1) {
    // finished rows -> out; survivors -> compacted spill
    if (tid < 64) {
      unsigned long long mk = __ballot(active);
      int base = 0;
      if (lane == 0 && mk) base = atomicAdd(cntp, __popcll(mk));
      base = __shfl(base, 0, 64);
      int rank = __popcll(mk & ((1ull << lane) - 1ull));
      int slot = active ? (base + rank) : -1;
      rowslot[tid] = slot;
      if (active) {
        spsum[slot]  = p_sum;
        saccum[slot] = accum;
        sidx[slot]   = oidx;
      } else {
        out[oidx] = accum;
      }
      if (tid == 0) anyact_s = (mk != 0ull) ? 1 : 0;
    }
    __syncthreads();
    if (anyact_s) {
      // dump cell regs into dead buffer Abuf[cur^1] (cols 0..511)
#pragma unroll
      for (int n = 0; n < 4; ++n)
#pragma unroll
        for (int m = 0; m < 4; ++m)
#pragma unroll
          for (int q = 0; q < 4; ++q)
            Abuf[cur ^ 1][m * 16 + lg * 4 + q][wave * 64 + n * 16 + lc] = (__bf16)cell[n][m][q];
      __syncthreads();
      for (int w = tid; w < RPB * 132; w += THR) {
        int r = w / 132, j = w - r * 132;
        int slot = rowslot[r];
        if (slot < 0) continue;
        if (j < 68)
          *(bf8*)(sstate + (size_t)slot * KD + j * 8) = *(const bf8*)&Abuf[cur][r][j * 8];
        else {
          int jj = j - 68;
          *(bf8*)(scell + (size_t)slot * 512 + jj * 8) = *(const bf8*)&Abuf[cur ^ 1][r][jj * 8];
        }
      }
    }
  } else {
    if (valid) out[oidx] = accum;
  }
}

extern "C" void kernel_launch(void* const* d_in, const int* in_sizes, int n_in,
                              void* d_out, int out_size, void* d_ws, size_t ws_size,
                              hipStream_t stream) {
  const float* x     = (const float*)d_in[0];
  const float* Wi_x  = (const float*)d_in[1];
  const float* bi_x  = (const float*)d_in[2];
  const float* Wi_h  = (const float*)d_in[3];
  const float* bi_h  = (const float*)d_in[4];
  const float* Wf_x  = (const float*)d_in[5];
  const float* bf_x  = (const float*)d_in[6];
  const float* Wf_h  = (const float*)d_in[7];
  const float* bf_h  = (const float*)d_in[8];
  const float* Wc_x  = (const float*)d_in[9];
  const float* bc_x  = (const float*)d_in[10];
  const float* Wc_h  = (const float*)d_in[11];
  const float* bc_h  = (const float*)d_in[12];
  const float* Wo_x  = (const float*)d_in[13];
  const float* bo_x  = (const float*)d_in[14];
  const float* Wo_h  = (const float*)d_in[15];
  const float* bo_h  = (const float*)d_in[16];
  const float* hW1   = (const float*)d_in[17];
  const float* hb1   = (const float*)d_in[18];
  const float* hW2   = (const float*)d_in[19];
  const float* hb2   = (const float*)d_in[20];
  const float* oW1   = (const float*)d_in[21];
  const float* ob1   = (const float*)d_in[22];
  const float* oW2   = (const float*)d_in[23];
  const float* ob2   = (const float*)d_in[24];
  const float* oW3   = (const float*)d_in[25];
  const float* ob3   = (const float*)d_in[26];

  char* p = (char*)d_ws;
  __bf16* whT   = (__bf16*)p;                       p += (size_t)2048 * KD * 2;   // 2,228,224
  __bf16* w1cat = (__bf16*)p;                       p += (size_t)256 * KD * 2;    //   278,528
  float*  w23   = (float*)p;                        p += 512;
  float*  b23   = (float*)p;                        p += 16;
  int*    cnt   = (int*)p;                          p += 240;                     // pad to 256B
  __bf16* sstate= (__bf16*)p;                       p += (size_t)NROW * KD * 2;   // 35.7 MB
  __bf16* scell = (__bf16*)p;                       p += (size_t)NROW * 512 * 2;  // 33.6 MB
  float*  spsum = (float*)p;                        p += (size_t)NROW * 4;
  float*  saccum= (float*)p;                        p += (size_t)NROW * 4;
  int*    sidx  = (int*)p;                          p += (size_t)NROW * 4;

  pack_all<<<dim3(4897), dim3(256), 0, stream>>>(
      Wi_h, Wf_h, Wc_h, Wo_h, Wi_x, Wf_x, Wc_x, Wo_x,
      bi_x, bf_x, bc_x, bo_x, bi_h, bf_h, bc_h, bo_h,
      oW1, ob1, hW1, hb1, oW2, ob2, oW3, ob3,
      whT, w1cat, w23, b23, cnt);
  act_pass<true><<<dim3(NROW / RPB), dim3(THR), 0, stream>>>(
      x, whT, w1cat, w23, b23, hW2, hb2,
      sstate, scell, spsum, saccum, sidx, cnt, (float*)d_out);
  act_pass<false><<<dim3(NROW / RPB), dim3(THR), 0, stream>>>(
      x, whT, w1cat, w23, b23, hW2, hb2,
      sstate, scell, spsum, saccum, sidx, cnt, (float*)d_out);
}